// Round 1
// baseline (407.528 us; speedup 1.0000x reference)
//
#include <hip/hip_runtime.h>
#include <math.h>

#define NMODES 64
#define NKNOTS 8
#define NSTEPS 80
#define ROW    1088      // NMODES + NMODES*NKNOTS*2
#define ROW4   272       // ROW/4
#define PREDF  10240     // NMODES*NSTEPS*2 floats per batch row
#define VECS   2560      // PREDF/4 float4 per batch row

// Evaluate one (m,t) spline point + centroid + rotation.
__device__ __forceinline__ void eval_pair(const float* __restrict__ s_kn,
                                          int m, int t, float cx, float cy,
                                          float rc, float rs, float X, float Y,
                                          float& px, float& py)
{
    // pos = t * (C-3)/T = t * 5/80
    float pos = (float)t * 0.0625f;
    int   sh  = (int)pos;                 // floor, pos >= 0
    float tt  = pos - (float)sh;
    float tt2 = tt * tt;
    float tt3 = tt2 * tt;
    const float inv6 = 1.0f / 6.0f;
    float omt = 1.0f - tt;
    float b0 = omt * omt * omt * inv6;
    float b1 = (3.0f * tt3 - 6.0f * tt2 + 4.0f) * inv6;
    float b2 = (-3.0f * tt3 + 3.0f * tt2 + 3.0f * tt + 1.0f) * inv6;
    float b3 = tt3 * inv6;
    // transposed knots: s_kn[m*16 + c*2 + d] ; 8-byte aligned float2 taps
    const float2* k = (const float2*)(s_kn + m * 16 + sh * 2);
    float2 k0 = k[0], k1 = k[1], k2 = k[2], k3 = k[3];
    float fx = b0 * k0.x + b1 * k1.x + b2 * k2.x + b3 * k3.x + cx;
    float fy = b0 * k0.y + b1 * k1.y + b2 * k2.y + b3 * k3.y + cy;
    px = rc * fx - rs * fy + X;
    py = rs * fx + rc * fy + Y;
}

__launch_bounds__(256, 4)
__global__ void head_kernel(const float* __restrict__ inputs,
                            const float* __restrict__ x,
                            const float* __restrict__ y,
                            const float* __restrict__ yaw,
                            const float* __restrict__ centroids,
                            float* __restrict__ pred,
                            float* __restrict__ conf,
                            float* __restrict__ knots_out)
{
    __shared__ float s_in[ROW];
    __shared__ float s_kn[NMODES * NKNOTS * 2];  // [m][c][d] transposed
    __shared__ float s_rot[4];

    const int tid = threadIdx.x;
    const int b   = blockIdx.x;

    // ---- stage full input row (1088 floats = 272 float4) ----
    const float4* row4  = (const float4*)(inputs + (size_t)b * ROW);
    float4*       s_in4 = (float4*)s_in;
    s_in4[tid] = row4[tid];
    if (tid < ROW4 - 256) s_in4[256 + tid] = row4[256 + tid];

    if (tid == 0) {
        float sy, cy;
        sincosf(yaw[b], &sy, &cy);
        s_rot[0] = cy;
        s_rot[1] = sy;
        s_rot[2] = x[b];
        s_rot[3] = y[b];
    }
    __syncthreads();

    // ---- knots output: straight copy of inputs[b, 64:1088] ----
    float4 kv = s_in4[16 + tid];  // floats 64 + 4*tid .. +3
    ((float4*)(knots_out + (size_t)b * 1024))[tid] = kv;

    // ---- transpose knots into s_kn: [m][c][d] so taps are float2 ----
    {
        int g = tid * 4;  // flat knot index within row (0..1023)
        const float* kvp = (const float*)&kv;
        #pragma unroll
        for (int e = 0; e < 4; ++e) {
            int gg = g + e;
            int m  = gg >> 4;         // /16
            int r  = gg & 15;
            int d  = r >> 3;          // /8
            int c  = r & 7;
            s_kn[(m << 4) + (c << 1) + d] = kvp[e];
        }
    }

    // ---- softmax over 64 modes (wave 0 only) ----
    if (tid < 64) {
        float v  = s_in[tid];
        float mx = v;
        #pragma unroll
        for (int off = 32; off > 0; off >>= 1)
            mx = fmaxf(mx, __shfl_xor(mx, off));
        float e = expf(v - mx);
        float sum = e;
        #pragma unroll
        for (int off = 32; off > 0; off >>= 1)
            sum += __shfl_xor(sum, off);
        conf[(size_t)b * NMODES + tid] = e / sum;
    }
    __syncthreads();

    const float rc = s_rot[0], rs = s_rot[1], X = s_rot[2], Y = s_rot[3];
    const float4* cent4 = (const float4*)centroids;   // 2560 float4, L2-resident
    float4* out4 = (float4*)(pred + (size_t)b * PREDF);

    // ---- pred: 2560 float4 per row, 10 per thread, coalesced 16B/lane ----
    #pragma unroll
    for (int j = 0; j < VECS / 256; ++j) {
        int idx = j * 256 + tid;          // float4 index = pair-pair index
        int m   = idx / 40;               // 40 float4 per mode
        int t0  = (idx - m * 40) * 2;     // first of two consecutive t
        float4 cent = cent4[idx];
        float4 o;
        eval_pair(s_kn, m, t0,     cent.x, cent.y, rc, rs, X, Y, o.x, o.y);
        eval_pair(s_kn, m, t0 + 1, cent.z, cent.w, rc, rs, X, Y, o.z, o.w);
        out4[idx] = o;
    }
}

extern "C" void kernel_launch(void* const* d_in, const int* in_sizes, int n_in,
                              void* d_out, int out_size, void* d_ws, size_t ws_size,
                              hipStream_t stream)
{
    const float* inputs    = (const float*)d_in[0];
    const float* x         = (const float*)d_in[1];
    const float* y         = (const float*)d_in[2];
    const float* yaw       = (const float*)d_in[3];
    const float* centroids = (const float*)d_in[4];

    const int B = in_sizes[1];  // x has B elements

    float* pred      = (float*)d_out;
    float* conf      = pred + (size_t)B * NMODES * NSTEPS * 2;
    float* knots_out = conf + (size_t)B * NMODES;

    head_kernel<<<B, 256, 0, stream>>>(inputs, x, y, yaw, centroids,
                                       pred, conf, knots_out);
}